// Round 5
// baseline (231.112 us; speedup 1.0000x reference)
//
#include <hip/hip_runtime.h>
#include <hip/hip_bf16.h>

// out[r][c] = x[r][c] * weight[c] + bias[c]
// x: (8192, 4096) f32, weight/bias: (4096,) f32, out: (8192, 4096) f32.
//
// R4 post-mortem: 8-way MLP helped less than predicted; nontemporal stores
// force all 134 MB of writes to HBM inside the kernel window. R3 counters
// showed FETCH_SIZE=65 MB -> x is half L3-warm from the harness restore.
// R5 change: CACHED stores — let the 256 MiB Infinity Cache absorb the write
// stream (drains after the kernel); in-window HBM traffic ~= read misses only.

typedef float f32x4 __attribute__((ext_vector_type(4)));

#define IN_SIZE   4096
#define COLS4     (IN_SIZE / 4)   // 1024 float4 per row
#define BATCH     8192
#define ROWS_PER_THREAD 8

__global__ __launch_bounds__(256) void diag_linear_kernel(
    const f32x4* __restrict__ x,
    const f32x4* __restrict__ w,
    const f32x4* __restrict__ b,
    f32x4* __restrict__ out)
{
    const int tid = blockIdx.x * blockDim.x + threadIdx.x;   // 0..1048575
    const int c4  = tid & (COLS4 - 1);                       // column group
    const int rg  = tid >> 10;                               // row group 0..1023
    const int r0  = rg * ROWS_PER_THREAD;

    const f32x4 wv = w[c4];
    const f32x4 bv = b[c4];

    const f32x4* xp = x + (size_t)r0 * COLS4 + c4;

    // Phase 1: issue all loads (8 outstanding global_load_dwordx4 per lane).
    f32x4 xv[ROWS_PER_THREAD];
#pragma unroll
    for (int i = 0; i < ROWS_PER_THREAD; ++i) {
        xv[i] = xp[(size_t)i * COLS4];
    }

    // Phase 2: compute + cached store (L2/L3 absorb; write-back overlaps
    // with later work instead of serializing inside this kernel).
    f32x4* op = out + (size_t)r0 * COLS4 + c4;
#pragma unroll
    for (int i = 0; i < ROWS_PER_THREAD; ++i) {
        op[(size_t)i * COLS4] = xv[i] * wv + bv;
    }
}

extern "C" void kernel_launch(void* const* d_in, const int* in_sizes, int n_in,
                              void* d_out, int out_size, void* d_ws, size_t ws_size,
                              hipStream_t stream) {
    const f32x4* x = (const f32x4*)d_in[0];
    const f32x4* w = (const f32x4*)d_in[1];
    const f32x4* b = (const f32x4*)d_in[2];
    f32x4* out = (f32x4*)d_out;

    // 1024 col-groups x 1024 row-groups (8 rows each) = 1,048,576 threads.
    // 4096 blocks x 256 threads; exact cover, no bounds checks.
    diag_linear_kernel<<<4096, 256, 0, stream>>>(x, w, b, out);
}